// Round 4
// baseline (549.642 us; speedup 1.0000x reference)
//
#include <hip/hip_runtime.h>
#include <cstdint>
#include <cstddef>

// ---------------------------------------------------------------------------
//   x:    [B=128, T=256, D=1024] fp32
//   Wk:   [1024, 512] per dir    Wr: [128, 512]    bias: [512]
//   xp[dir][t*128+b][512] = x[b,t,:] @ Wk + bias   (bf16, t-major, bias folded)
//   LSTM R3b: M=seq / N=gate-dim MFMA orientation. 128 blocks x 512 thr
//   (8 waves, 2/SIMD). Wave w owns dims [16w,16w+16) x all 4 gates:
//   16 MFMAs/wave (4 indep chains depth 4), Wr frags = 64 VGPR (resident).
//   Quad-0 lanes get all 4 gates of their dim in MFMA output regs ->
//   activation in-lane, NO z LDS round trip. One lite barrier per step.
//   (R3's separate Wr^T kernel/buffer removed: workspace footprint is
//   byte-identical to the passing R0-R2 versions; Wr frags built in-kernel.)
// ---------------------------------------------------------------------------

typedef __attribute__((ext_vector_type(8))) short short8;
typedef __attribute__((ext_vector_type(4))) float f32x4;
typedef __attribute__((address_space(1))) unsigned int gas_uint;
typedef __attribute__((address_space(3))) unsigned int las_uint;

__device__ __forceinline__ unsigned short f2b(float f) {
    unsigned int u = __float_as_uint(f);
    u += 0x7FFFu + ((u >> 16) & 1u);          // RNE
    return (unsigned short)(u >> 16);
}
__device__ __forceinline__ float b2f(unsigned short u) {
    return __uint_as_float(((unsigned int)u) << 16);
}
__device__ __forceinline__ float sigmoidf_(float z) { return 1.0f / (1.0f + __expf(-z)); }
__device__ __forceinline__ float tanhf_(float z) {
    float e = __expf(2.0f * z);
    return 1.0f - 2.0f / (e + 1.0f);
}

// workgroup barrier WITHOUT the vmcnt(0) drain __syncthreads would emit:
// LDS ordering only — outstanding global prefetch loads stay in flight.
#define LITE_BARRIER() asm volatile("s_waitcnt lgkmcnt(0)\n\ts_barrier" ::: "memory")

// async global->LDS 16B
__device__ __forceinline__ void async_ld16(const unsigned short* g, unsigned short* l) {
    __builtin_amdgcn_global_load_lds(
        (gas_uint*)(uintptr_t)g,
        (las_uint*)(uintptr_t)(unsigned int)(uintptr_t)l,
        16, 0, 0);
}

// ---------------------------------------------------------------------------
// Kernel 1: x fp32 -> bf16
// ---------------------------------------------------------------------------
__global__ void conv_x(const float* __restrict__ x, unsigned short* __restrict__ xb, int n8) {
    int idx = blockIdx.x * blockDim.x + threadIdx.x;
    int stride = gridDim.x * blockDim.x;
    for (int i = idx; i < n8; i += stride) {
        const float4* p = ((const float4*)x) + (size_t)i * 2;
        float4 a = p[0], b = p[1];
        short8 r;
        r[0] = (short)f2b(a.x); r[1] = (short)f2b(a.y);
        r[2] = (short)f2b(a.z); r[3] = (short)f2b(a.w);
        r[4] = (short)f2b(b.x); r[5] = (short)f2b(b.y);
        r[6] = (short)f2b(b.z); r[7] = (short)f2b(b.w);
        *(((short8*)xb) + i) = r;
    }
}

// ---------------------------------------------------------------------------
// Kernel 2: transpose + convert Wk [1024][512] -> Wk_t [512][1024] bf16
// ---------------------------------------------------------------------------
__global__ void conv_wk(const float* __restrict__ wf, const float* __restrict__ wb,
                        unsigned short* __restrict__ wt) {
    int dir = blockIdx.y;
    const float* w = dir ? wb : wf;
    int id = blockIdx.x * blockDim.x + threadIdx.x;
    int g = id >> 10, d = id & 1023;
    wt[(size_t)dir * 524288 + id] = f2b(w[d * 512 + g]);
}

// ---------------------------------------------------------------------------
// Kernel 3: GEMM xp = A[32768,1024] @ Wk_t^T + bias -> bf16 t-major [t*128+b][512]
// (unchanged: 128x128 tile, BK=64, global_load_lds w=16, XOR swizzle)
// ---------------------------------------------------------------------------
__global__ __launch_bounds__(256, 2) void gemm_xp(
    const unsigned short* __restrict__ A,
    const unsigned short* __restrict__ Wt,
    const float* __restrict__ bf_, const float* __restrict__ bb_,
    unsigned short* __restrict__ XP)
{
    __shared__ unsigned short As[128 * 64];
    __shared__ unsigned short Bs[128 * 64];

    const int tid  = threadIdx.x;
    const int dir  = blockIdx.z;
    const int tm   = blockIdx.x;             // 0..255
    const int tn   = blockIdx.y;             // 0..3
    const int w    = tid >> 6;
    const int lane = tid & 63;
    const int lanelo = lane & 15;
    const int quad = lane >> 4;
    const int wm = w & 1, wn = w >> 1;

    const unsigned short* Bmat = Wt + (size_t)dir * 524288;
    const float* bias = dir ? bb_ : bf_;
    unsigned short* out = XP + (size_t)dir * 16777216;

    const unsigned short* ga[4];
    const unsigned short* gb[4];
    unsigned short* la[4];
    unsigned short* lb[4];
#pragma unroll
    for (int c = 0; c < 4; ++c) {
        int p = c * 256 + tid;
        int row = p >> 3;
        int lc = (p & 7) ^ (row & 7);
        ga[c] = A    + (size_t)(tm * 128 + row) * 1024 + lc * 8;
        gb[c] = Bmat + (size_t)(tn * 128 + row) * 1024 + lc * 8;
        int ub = (c * 256 + (tid & ~63)) * 8;
        la[c] = As + ub;
        lb[c] = Bs + ub;
    }

    f32x4 acc[4][4];
#pragma unroll
    for (int i = 0; i < 4; i++)
#pragma unroll
        for (int j = 0; j < 4; j++) acc[i][j] = (f32x4){0.f, 0.f, 0.f, 0.f};

    for (int kt = 0; kt < 16; ++kt) {
        __syncthreads();
#pragma unroll
        for (int c = 0; c < 4; ++c) {
            async_ld16(ga[c] + kt * 64, la[c]);
            async_ld16(gb[c] + kt * 64, lb[c]);
        }
        __syncthreads();
#pragma unroll
        for (int ks = 0; ks < 2; ++ks) {
            short8 af[4], bfr[4];
#pragma unroll
            for (int i = 0; i < 4; ++i) {
                int row = wm * 64 + i * 16 + lanelo;
                af[i] = *(const short8*)(As + row * 64 + (((ks * 4 + quad) ^ (row & 7)) * 8));
            }
#pragma unroll
            for (int j = 0; j < 4; ++j) {
                int row = wn * 64 + j * 16 + lanelo;
                bfr[j] = *(const short8*)(Bs + row * 64 + (((ks * 4 + quad) ^ (row & 7)) * 8));
            }
#pragma unroll
            for (int i = 0; i < 4; ++i)
#pragma unroll
                for (int j = 0; j < 4; ++j)
                    acc[i][j] = __builtin_amdgcn_mfma_f32_16x16x32_bf16(af[i], bfr[j], acc[i][j], 0, 0, 0);
        }
    }

    float biasv[4];
#pragma unroll
    for (int j = 0; j < 4; ++j)
        biasv[j] = bias[tn * 128 + wn * 64 + j * 16 + lanelo];

#pragma unroll
    for (int i = 0; i < 4; ++i) {
#pragma unroll
        for (int r = 0; r < 4; ++r) {
            int gr = tm * 128 + wm * 64 + i * 16 + quad * 4 + r;   // = b*256 + t
            int bb = gr >> 8, tt = gr & 255;
            size_t orow = (size_t)(tt * 128 + bb) * 512;
#pragma unroll
            for (int j = 0; j < 4; ++j) {
                int col = tn * 128 + wn * 64 + j * 16 + lanelo;
                out[orow + col] = f2b(acc[i][j][r] + biasv[j]);
            }
        }
    }
}

// ---------------------------------------------------------------------------
// Kernel 4: LSTM recurrence. 128 blocks x 512 thr; block = (dir, seq-pair).
// M=seq orientation:  A = h [2 x 128] (rows 0,1 valid), B = Wr [128 x 512].
// Wave w: 4 gate-tiles (N = g*128 + [16w,16w+16)) x 4 k-steps = 16 MFMAs.
// D: col=lane&15 = dim-in-strip, row=quad*4+reg = seq -> quad-0 lanes hold
// z for all 4 gates of dim (16w+lanelo), seqs in regs [0],[1]. Activation
// fully in-lane; h written back as 2 b16 LDS stores. One barrier/step.
// ---------------------------------------------------------------------------
__global__ __launch_bounds__(512, 2) void lstm_rec(
    const unsigned short* __restrict__ XP,    // [2][256*128][512] bf16, bias folded
    const float* __restrict__ Wfr, const float* __restrict__ Wbr,
    float* __restrict__ Hout)                 // [2][128][128]
{
    __shared__ unsigned short h_lds[2][2][128]; // [buf][seq][dim]

    const int tid    = threadIdx.x;
    const int w      = tid >> 6;              // 0..7
    const int lane   = tid & 63;
    const int lanelo = lane & 15;
    const int quad   = lane >> 4;
    const int dir    = blockIdx.x >> 6;
    const int b0     = (blockIdx.x & 63) * 2;
    const int SB     = w * 16;                // dim strip base
    const int dim    = SB + lanelo;

    const float* Wr = dir ? Wbr : Wfr;
    const unsigned short* xp = XP + (size_t)dir * 16777216;

    // --- one-time B-fragments: wrf[g][ks][j] = Wr[ks*32+quad*8+j][g*128+dim]
    //     (fp32 -> bf16 in-register; 16 frags = 64 VGPR, loop-resident) ---
    short8 wrf[4][4];
#pragma unroll
    for (int g = 0; g < 4; ++g)
#pragma unroll
        for (int ks = 0; ks < 4; ++ks) {
            short8 f;
#pragma unroll
            for (int j = 0; j < 8; ++j)
                f[j] = (short)f2b(Wr[(size_t)(ks * 32 + quad * 8 + j) * 512 + g * 128 + dim]);
            wrf[g][ks] = f;
        }

    if (tid < 256) ((unsigned short*)h_lds)[tid] = 0;   // zero h buffer 0

    // A-fragments of h; only lanes with lanelo<2 ever load real rows.
    short8 hfrag[4];
    const short8 hz = (short8){0, 0, 0, 0, 0, 0, 0, 0};
#pragma unroll
    for (int ks = 0; ks < 4; ++ks) hfrag[ks] = hz;

    float c0v = 0.f, c1v = 0.f, h0v = 0.f, h1v = 0.f;

    // x pointer: quad-0 lanes' addresses are the meaningful ones; other quads
    // duplicate them (same cachelines, broadcast, no divergence).
    const ptrdiff_t xstep = dir ? -65536 : 65536;       // elements per t
    const unsigned short* xb_ =
        xp + (size_t)(dir ? 255 : 0) * 65536 + (size_t)b0 * 512 + dim;

    unsigned int xA[8], xB[8];
#pragma unroll
    for (int s = 0; s < 2; ++s)
#pragma unroll
        for (int g = 0; g < 4; ++g) xA[s * 4 + g] = xb_[s * 512 + g * 128];
    xb_ += xstep;
#pragma unroll
    for (int s = 0; s < 2; ++s)
#pragma unroll
        for (int g = 0; g < 4; ++g) xB[s * 4 + g] = xb_[s * 512 + g * 128];
    xb_ += xstep;

    LITE_BARRIER();                           // h_lds[0] zeros visible

    const f32x4 kZ = (f32x4){0.f, 0.f, 0.f, 0.f};

#define LSTM_STEP(XC, CUR, NXT)                                                  \
    {                                                                            \
        /* consume x loaded 2 steps ago; reissue prefetch into same regs */      \
        float xv[8];                                                             \
        _Pragma("unroll")                                                        \
        for (int q = 0; q < 8; ++q) xv[q] = b2f((unsigned short)XC[q]);          \
        _Pragma("unroll")                                                        \
        for (int s = 0; s < 2; ++s)                                              \
            _Pragma("unroll")                                                    \
            for (int g = 0; g < 4; ++g) XC[s * 4 + g] = xb_[s * 512 + g * 128];  \
        xb_ += xstep;                                                            \
        /* masked A-frag read: only rows 0,1 are real (2 lanes/wave) */          \
        if (lanelo < 2) {                                                        \
            _Pragma("unroll")                                                    \
            for (int ks = 0; ks < 4; ++ks)                                       \
                hfrag[ks] = *(const short8*)(&h_lds[CUR][lanelo][ks * 32 + quad * 8]); \
        }                                                                        \
        /* 16 MFMAs: 4 independent gate chains, depth 4 */                       \
        f32x4 z0 = __builtin_amdgcn_mfma_f32_16x16x32_bf16(hfrag[0], wrf[0][0], kZ, 0, 0, 0); \
        f32x4 z1 = __builtin_amdgcn_mfma_f32_16x16x32_bf16(hfrag[0], wrf[1][0], kZ, 0, 0, 0); \
        f32x4 z2 = __builtin_amdgcn_mfma_f32_16x16x32_bf16(hfrag[0], wrf[2][0], kZ, 0, 0, 0); \
        f32x4 z3 = __builtin_amdgcn_mfma_f32_16x16x32_bf16(hfrag[0], wrf[3][0], kZ, 0, 0, 0); \
        _Pragma("unroll")                                                        \
        for (int ks = 1; ks < 4; ++ks) {                                         \
            z0 = __builtin_amdgcn_mfma_f32_16x16x32_bf16(hfrag[ks], wrf[0][ks], z0, 0, 0, 0); \
            z1 = __builtin_amdgcn_mfma_f32_16x16x32_bf16(hfrag[ks], wrf[1][ks], z1, 0, 0, 0); \
            z2 = __builtin_amdgcn_mfma_f32_16x16x32_bf16(hfrag[ks], wrf[2][ks], z2, 0, 0, 0); \
            z3 = __builtin_amdgcn_mfma_f32_16x16x32_bf16(hfrag[ks], wrf[3][ks], z3, 0, 0, 0); \
        }                                                                        \
        /* activation: quad-0 lanes own (dim, both seqs); all gates local */     \
        if (quad == 0) {                                                         \
            float zi0 = z0[0] + xv[0], zf0 = z1[0] + xv[1];                      \
            float zg0 = z2[0] + xv[2], zo0 = z3[0] + xv[3];                      \
            float zi1 = z0[1] + xv[4], zf1 = z1[1] + xv[5];                      \
            float zg1 = z2[1] + xv[6], zo1 = z3[1] + xv[7];                      \
            float i0 = sigmoidf_(zi0), f0 = sigmoidf_(zf0);                      \
            float g0 = tanhf_(zg0),    o0 = sigmoidf_(zo0);                      \
            c0v = f0 * c0v + i0 * g0;                                            \
            h0v = o0 * tanhf_(c0v);                                              \
            float i1 = sigmoidf_(zi1), f1 = sigmoidf_(zf1);                      \
            float g1 = tanhf_(zg1),    o1 = sigmoidf_(zo1);                      \
            c1v = f1 * c1v + i1 * g1;                                            \
            h1v = o1 * tanhf_(c1v);                                              \
            h_lds[NXT][0][dim] = f2b(h0v);                                       \
            h_lds[NXT][1][dim] = f2b(h1v);                                       \
        }                                                                        \
        LITE_BARRIER();                                                          \
    }

    for (int t = 0; t < 256; t += 2) {
        LSTM_STEP(xA, 0, 1)
        LSTM_STEP(xB, 1, 0)
    }
#undef LSTM_STEP

    if (quad == 0) {
        Hout[(size_t)(dir * 128 + b0) * 128 + dim]     = h0v;
        Hout[(size_t)(dir * 128 + b0 + 1) * 128 + dim] = h1v;
    }
}

// ---------------------------------------------------------------------------
// Kernel 5: MLP head
// ---------------------------------------------------------------------------
__global__ void mlp_head(const float* __restrict__ Hout,
                         const float* __restrict__ W1, const float* __restrict__ b1,
                         const float* __restrict__ W2, const float* __restrict__ b2,
                         float* __restrict__ out)
{
    __shared__ float y1[32];
    int b = blockIdx.x;
    int j = threadIdx.x;
    const float* hf = Hout + (size_t)b * 128;
    const float* hb = Hout + (size_t)(128 + b) * 128;
    if (j < 32) {
        float acc = b1[j];
        for (int k = 0; k < 128; ++k) acc += hf[k] * W1[k * 32 + j];
        for (int k = 0; k < 128; ++k) acc += hb[k] * W1[(128 + k) * 32 + j];
        y1[j] = fmaxf(acc, 0.0f);
    }
    __syncthreads();
    if (j < 2) {
        float z = b2[j];
        for (int k = 0; k < 32; ++k) z += y1[k] * W2[k * 2 + j];
        out[b * 2 + j] = 1.0f / (1.0f + __expf(-z));
    }
}

// ---------------------------------------------------------------------------
extern "C" void kernel_launch(void* const* d_in, const int* in_sizes, int n_in,
                              void* d_out, int out_size, void* d_ws, size_t ws_size,
                              hipStream_t stream) {
    const float* x    = (const float*)d_in[0];
    const float* Wf_k = (const float*)d_in[1];
    const float* Wf_r = (const float*)d_in[2];
    const float* bf   = (const float*)d_in[3];
    const float* Wb_k = (const float*)d_in[4];
    const float* Wb_r = (const float*)d_in[5];
    const float* bb   = (const float*)d_in[6];
    const float* W1   = (const float*)d_in[7];
    const float* b1   = (const float*)d_in[8];
    const float* W2   = (const float*)d_in[9];
    const float* b2   = (const float*)d_in[10];
    float* out = (float*)d_out;

    char* ws = (char*)d_ws;
    const size_t OFF_XB   = 0;                        // 67,108,864 B
    const size_t OFF_WT   = 67108864;                 //  2,097,152 B
    const size_t OFF_HOUT = OFF_WT + 2097152;         //    131,072 B
    const size_t OFF_XP   = OFF_HOUT + 131072;        // 67,108,864 B (bf16)

    unsigned short* xb  = (unsigned short*)(ws + OFF_XB);
    unsigned short* wt  = (unsigned short*)(ws + OFF_WT);
    float*          ho  = (float*)(ws + OFF_HOUT);
    unsigned short* xpb = (unsigned short*)(ws + OFF_XP);

    conv_x<<<dim3(2048), dim3(256), 0, stream>>>(x, xb, 33554432 / 8);
    conv_wk<<<dim3(2048, 2), dim3(256), 0, stream>>>(Wf_k, Wb_k, wt);
    gemm_xp<<<dim3(256, 4, 2), dim3(256), 0, stream>>>(xb, wt, bf, bb, xpb);
    lstm_rec<<<dim3(128), dim3(512), 0, stream>>>(xpb, Wf_r, Wb_r, ho);
    mlp_head<<<dim3(128), dim3(64), 0, stream>>>(ho, W1, b1, W2, b2, out);
}